// Round 2
// baseline (708.912 us; speedup 1.0000x reference)
//
#include <hip/hip_runtime.h>

// Problem constants
#define BB   512
#define CC   22
#define TT   1000
#define HH   64
#define NCLS 4
#define TC   250          // time chunk staged in LDS
#define NCHUNK (TT / TC)
#define XSL  16           // h2 slots per xs row: two 8-slot halves (64 B rows)

typedef _Float16 f16;
typedef __attribute__((ext_vector_type(2))) _Float16 h2;

// fast activations: v_exp + v_rcp (1 ulp) instead of the IEEE div sequence.
__device__ __forceinline__ float sigm(float x) {
    float e = __expf(-x);
    return __builtin_amdgcn_rcpf(1.0f + e);
}
__device__ __forceinline__ float tanh_(float x) {
    float e = __expf(-2.0f * fabsf(x));   // (0,1], no overflow
    float r = (1.0f - e) * __builtin_amdgcn_rcpf(1.0f + e);
    return copysignf(r, x);
}

__device__ __forceinline__ h2 u2h(unsigned u) {
    union { unsigned u; h2 h; } c; c.u = u; return c.h;
}
__device__ __forceinline__ unsigned h2u(h2 h) {
    union { unsigned u; h2 h; } c; c.h = h; return c.u;
}

// R6 = R5 resubmit (bench infra failed; no evidence against the design).
// 2-wave K-split. One block (128 thr = 2 waves) per batch row; lane = hidden
// unit in BOTH waves. Wave w owns K-half w of the recurrent dot (h[32w..32w+31])
// and channel-half w of the input dot (ch 0-11 / 12-21). Per step each wave
// computes 4 partial gate sums (96 fdot2 vs 172 before), exchanges partials
// through double-buffered LDS with ONE barrier, then both waves redundantly run
// the (cheap) activation chain so each holds h for its lane.
//
// Why: R4's counters showed VGPR_Count=132 < the 176 pinned weight regs -> the
// weights were spilled (AGPR/scratch) and re-read every one of the 1000 steps,
// on top of a 1-wave/SIMD launch with zero latency hiding. Halving the per-wave
// weight set to 92 regs kills the spill by construction; halving the serial
// fdot2 chain and doubling wave coverage attacks the exposed-latency step time
// (measured 1536 cyc/step vs ~500 modeled).
//
// Race-freedom invariants:
//  * partials: write part[tt&1][w], barrier, read part[tt&1][1-w]. A wave's
//    write two steps ahead is fenced by the intervening barrier (partner's
//    read precedes its barrier arrival).
//  * hbuf: both waves write bit-identical h (float add is commutative, both
//    sum the same two partials), and each wave reads only slots its OWN
//    lanes wrote -> in-order DS pipe, no barrier needed.
//  * xs: chunk staging happens after the last in-loop barrier of the previous
//    chunk (readers' xs loads all precede that barrier); one barrier after
//    staging publishes the new chunk to both waves.
__global__ __launch_bounds__(128, 1) void lstm_wave2(
    const float* __restrict__ x,     // [B, C, T]
    const float* __restrict__ W_ih,  // [4H, C]
    const float* __restrict__ W_hh,  // [4H, H]
    const float* __restrict__ b_ih,  // [4H]
    const float* __restrict__ b_hh,  // [4H]
    const float* __restrict__ W_fc,  // [NCLS, T*H]
    const float* __restrict__ b_fc,  // [NCLS]
    float* __restrict__ out)         // [B, NCLS]
{
    __shared__ __align__(16) h2    xs[TC][XSL];         // 16000 B: x chunk, f16 pairs
    __shared__ __align__(16) f16   hbuf[HH];            // 128 B: h broadcast
    __shared__ __align__(16) float part[2][2][HH][4];   // 4096 B: dbuf partials
    __shared__ float tmp4[NCLS];                        // final logit exchange

    const int tid  = threadIdx.x;
    const int w    = tid >> 6;       // wave id: K-half / channel-half owner
    const int lane = tid & 63;       // hidden unit
    const int r    = blockIdx.x;     // batch row

    // ---- per-lane weights (this wave's halves only): 92 regs, then pin ----
    unsigned whh[4][16];      // W_hh[row][32w + 2k..2k+1] as f16 pairs: 64 VGPR
    unsigned wih[4][6];       // W_ih[row][12w + 2k..2k+1]: 24 VGPR (w1 k=5 -> 0)
    float    bias[4];         // added by wave 0 only (no double count)
    #pragma unroll
    for (int g = 0; g < 4; ++g) {
        const int row = g * HH + lane;
        const float* wr = W_hh + row * HH + 32 * w;
        #pragma unroll
        for (int k = 0; k < 16; ++k)
            whh[g][k] = h2u(h2{(f16)wr[2 * k], (f16)wr[2 * k + 1]});
        const float* wi = W_ih + row * CC + 12 * w;
        #pragma unroll
        for (int k = 0; k < 6; ++k) {
            unsigned v = 0u;                    // guard OOB: w1 has only 5 pairs
            if (w == 0 || k < 5)
                v = h2u(h2{(f16)wi[2 * k], (f16)wi[2 * k + 1]});
            wih[g][k] = v;
        }
        bias[g] = (w == 0) ? (b_ih[row] + b_hh[row]) : 0.0f;
    }
    #pragma unroll
    for (int g = 0; g < 4; ++g) {
        #pragma unroll
        for (int k = 0; k < 16; ++k) asm volatile("" : "+v"(whh[g][k]));
        #pragma unroll
        for (int k = 0; k < 6; ++k)  asm volatile("" : "+v"(wih[g][k]));
        asm volatile("" : "+v"(bias[g]));
    }

    hbuf[lane] = (f16)0.0f;          // both waves write identical value
    float c = 0.0f;
    float fca = 0.0f, fcb = 0.0f;    // wave w accumulates classes 2w, 2w+1
    const float* pa = W_fc + (size_t)(2 * w)     * (TT * HH) + lane;
    const float* pb = W_fc + (size_t)(2 * w + 1) * (TT * HH) + lane;
    const float* xrow = x + (size_t)r * (CC * TT);

    for (int chunk = 0; chunk < NCHUNK; ++chunk) {
        // ---- stage x chunk into LDS, both waves cooperate (64 B rows) ----
        for (int tb = 0; tb < TC; tb += 128) {
            const int t = tb + tid;
            if (t < TC) {
                const float* gx = xrow + chunk * TC + t;   // stride TT per channel
                union { h2 h[XSL]; uint4 q[4]; } U;
                #pragma unroll
                for (int k = 0; k < 6; ++k)                // half 0: ch 0..11
                    U.h[k] = h2{(f16)gx[(2 * k) * TT], (f16)gx[(2 * k + 1) * TT]};
                U.h[6] = h2{(f16)0.0f, (f16)0.0f};
                U.h[7] = h2{(f16)0.0f, (f16)0.0f};
                #pragma unroll
                for (int j = 0; j < 5; ++j)                // half 1: ch 12..21
                    U.h[8 + j] = h2{(f16)gx[(12 + 2 * j) * TT], (f16)gx[(13 + 2 * j) * TT]};
                U.h[13] = h2{(f16)0.0f, (f16)0.0f};
                U.h[14] = h2{(f16)0.0f, (f16)0.0f};
                U.h[15] = h2{(f16)0.0f, (f16)0.0f};
                uint4* dst = (uint4*)&xs[t][0];
                dst[0] = U.q[0]; dst[1] = U.q[1]; dst[2] = U.q[2]; dst[3] = U.q[3];
            }
        }
        __syncthreads();   // publish xs across waves

        for (int tt = 0; tt < TC; ++tt) {
            // W_fc loads early: L2-hit latency drains before the barrier
            float wa = *pa, wb = *pb;
            pa += HH; pb += HH;

            // own h-half broadcast (4 x ds_read_b128, all lanes same address)
            union { uint4 q[4]; h2 h[16]; } H;
            const uint4* hr = (const uint4*)(hbuf + 32 * w);
            #pragma unroll
            for (int i = 0; i < 4; ++i) H.q[i] = hr[i];

            // own x-half: 1x ds_read_b128 + 1x ds_read_b64 broadcast
            __align__(16) h2 X[6];
            {
                const h2* xp = &xs[tt][8 * w];
                *(uint4*)&X[0] = *(const uint4*)xp;
                *(uint2*)&X[4] = *(const uint2*)(xp + 4);
            }

            // partial gate dots: x part (independent of h read) then h part
            float a0 = bias[0], a1 = bias[1], a2 = bias[2], a3 = bias[3];
            #pragma unroll
            for (int k = 0; k < 6; ++k) {
                a0 = __builtin_amdgcn_fdot2(X[k], u2h(wih[0][k]), a0, false);
                a1 = __builtin_amdgcn_fdot2(X[k], u2h(wih[1][k]), a1, false);
                a2 = __builtin_amdgcn_fdot2(X[k], u2h(wih[2][k]), a2, false);
                a3 = __builtin_amdgcn_fdot2(X[k], u2h(wih[3][k]), a3, false);
            }
            #pragma unroll
            for (int k = 0; k < 16; ++k) {
                a0 = __builtin_amdgcn_fdot2(H.h[k], u2h(whh[0][k]), a0, false);
                a1 = __builtin_amdgcn_fdot2(H.h[k], u2h(whh[1][k]), a1, false);
                a2 = __builtin_amdgcn_fdot2(H.h[k], u2h(whh[2][k]), a2, false);
                a3 = __builtin_amdgcn_fdot2(H.h[k], u2h(whh[3][k]), a3, false);
            }

            // cross-wave partial exchange (double-buffered, ONE barrier)
            const int buf = tt & 1;
            float4 mine; mine.x = a0; mine.y = a1; mine.z = a2; mine.w = a3;
            *(float4*)&part[buf][w][lane][0] = mine;
            __syncthreads();
            float4 oth = *(const float4*)&part[buf][1 - w][lane][0];
            a0 += oth.x; a1 += oth.y; a2 += oth.z; a3 += oth.w;

            // lane-local LSTM update (redundant in both waves, bit-identical)
            float iv = sigm(a0), fv = sigm(a1), gv = tanh_(a2), ov = sigm(a3);
            c = fv * c + iv * gv;
            float h = ov * tanh_(c);

            // fused FC accumulation: 2 classes per wave
            fca += h * wa;
            fcb += h * wb;

            // publish h (each wave later reads only its OWN lanes' slots)
            hbuf[lane] = (f16)h;
        }
    }

    // ---- FC reduce over hid (wave shuffle), then softmax over 4 logits ----
    #pragma unroll
    for (int off = 32; off; off >>= 1) {
        fca += __shfl_down(fca, off);
        fcb += __shfl_down(fcb, off);
    }
    if (lane == 0) {
        tmp4[2 * w]     = fca + b_fc[2 * w];
        tmp4[2 * w + 1] = fcb + b_fc[2 * w + 1];
    }
    __syncthreads();
    if (tid == 0) {
        float l0 = tmp4[0], l1 = tmp4[1], l2 = tmp4[2], l3 = tmp4[3];
        float m  = fmaxf(fmaxf(l0, l1), fmaxf(l2, l3));
        float e0 = __expf(l0 - m), e1 = __expf(l1 - m);
        float e2 = __expf(l2 - m), e3 = __expf(l3 - m);
        float is = __builtin_amdgcn_rcpf(e0 + e1 + e2 + e3);
        float4 o; o.x = e0 * is; o.y = e1 * is; o.z = e2 * is; o.w = e3 * is;
        *(float4*)(out + r * NCLS) = o;
    }
}

extern "C" void kernel_launch(void* const* d_in, const int* in_sizes, int n_in,
                              void* d_out, int out_size, void* d_ws, size_t ws_size,
                              hipStream_t stream) {
    const float* x    = (const float*)d_in[0];
    const float* W_ih = (const float*)d_in[1];
    const float* W_hh = (const float*)d_in[2];
    const float* b_ih = (const float*)d_in[3];
    const float* b_hh = (const float*)d_in[4];
    const float* W_fc = (const float*)d_in[5];
    const float* b_fc = (const float*)d_in[6];
    float* out = (float*)d_out;

    lstm_wave2<<<BB, 128, 0, stream>>>(x, W_ih, W_hh, b_ih, b_hh, W_fc, b_fc, out);
}